// Round 6
// baseline (5555.257 us; speedup 1.0000x reference)
//
#include <hip/hip_runtime.h>

#define TSTEPS 50
#define NB (2048 * 256)   // floats per h half-plane (256 rows x 2048 seqs)

__device__ __forceinline__ float sigm(float x) { return 1.0f / (1.0f + expf(-x)); }
__device__ __forceinline__ float gelu_t(float x) {
  float x3 = x * x * x;
  return 0.5f * x * (1.0f + tanhf(0.7978845608028654f * (x + 0.044715f * x3)));
}

// ZA[m][j][g] += a[m] * w[j][g]  (2 seqs x 2 jcols x 4 gates = 16 FMA)
// NOTE: param must NOT be named 'z' -- it would capture the .z member accesses.
#define FMA16Z(ZA, a, wa, wb) do { \
  ZA[0][0][0]+=(a).x*(wa).x; ZA[0][0][1]+=(a).x*(wa).y; ZA[0][0][2]+=(a).x*(wa).z; ZA[0][0][3]+=(a).x*(wa).w; \
  ZA[0][1][0]+=(a).x*(wb).x; ZA[0][1][1]+=(a).x*(wb).y; ZA[0][1][2]+=(a).x*(wb).z; ZA[0][1][3]+=(a).x*(wb).w; \
  ZA[1][0][0]+=(a).y*(wa).x; ZA[1][0][1]+=(a).y*(wa).y; ZA[1][0][2]+=(a).y*(wa).z; ZA[1][0][3]+=(a).y*(wa).w; \
  ZA[1][1][0]+=(a).y*(wb).x; ZA[1][1][1]+=(a).y*(wb).y; ZA[1][1][2]+=(a).y*(wb).z; ZA[1][1][3]+=(a).y*(wb).w; \
} while (0)

// XCD-local barrier: the 16 blocks of one m-group are co-XCD (blk%8 = mg%8).
// Release: __syncthreads' vmcnt-drain (stores reach L2, the coherence point).
// Acquire: invalidate per-CU vector L1 only; L2 keeps W resident.
__device__ __forceinline__ void mg_barrier(unsigned* bar, unsigned target) {
  __syncthreads();
  if (threadIdx.x == 0) {
    atomicAdd(bar, 1u);
    while (atomicAdd(bar, 0u) < target) __builtin_amdgcn_s_sleep(2);
    asm volatile("buffer_inv sc0" ::: "memory");
  }
  __syncthreads();
}

// Pack W per jcol-pair stream: Wp[jp][k][8] = gates g0..g3 of jc0=2jp, then jc1.
__global__ void __launch_bounds__(256)
pack_w(const float* __restrict__ Wx1, const float* __restrict__ Wh1,
       const float* __restrict__ Wx2, const float* __restrict__ Wh2,
       float* __restrict__ Wp1, float* __restrict__ Wp2, unsigned* __restrict__ bar) {
  const int idx = blockIdx.x * 256 + threadIdx.x;
  if (blockIdx.x == 0 && threadIdx.x < 256) bar[threadIdx.x] = 0u;
  if (idx < 128 * 272 * 8) {
    int e = idx & 7, k = (idx >> 3) % 272, jp = idx / (272 * 8);
    int col = ((e & 3) << 8) + (jp << 1) + (e >> 2);
    Wp1[idx] = (k < 16) ? Wx1[(k << 10) + col] : Wh1[((k - 16) << 10) + col];
  }
  if (idx < 128 * 512 * 8) {
    int e = idx & 7, k = (idx >> 3) & 511, jp = idx >> 12;
    int col = ((e & 3) << 8) + (jp << 1) + (e >> 2);
    Wp2[idx] = (k < 256) ? Wx2[(k << 10) + col] : Wh2[((k - 256) << 10) + col];
  }
}

// x[seq][t*16+d] -> xT[t*16+d][seq]
__global__ void __launch_bounds__(256)
transpose_x(const float* __restrict__ x, float* __restrict__ xT) {
  __shared__ float Ts[64][65];
  const int st = blockIdx.x & 31;
  const int tt = blockIdx.x >> 5;
  const int s0 = st << 6, t0 = tt << 6;
  const int r = threadIdx.x >> 6;
  const int c = threadIdx.x & 63;
  #pragma unroll
  for (int i = 0; i < 16; ++i) {
    int row = r + (i << 2);
    int td = t0 + c;
    if (td < 800) Ts[row][c] = x[(s0 + row) * 800 + td];
  }
  __syncthreads();
  #pragma unroll
  for (int i = 0; i < 16; ++i) {
    int row = r + (i << 2);
    int td = t0 + row;
    if (td < 800) xT[td * 2048 + s0 + c] = Ts[c][row];
  }
}

// Persistent fused 2-layer LSTM + time-mean pool.
// grid 256 = 16 mg (128 seqs, XCD-aligned: blk&15) x 16 jg (16 jcols).
// block 512 = 8 waves; wave wv owns jcol pair jc0=2*(jg*8+wv); lanes = 128 seqs.
// Phase p: rows x[p] -> z1; rows h1[p-1] -> BOTH z1 (W1h) and z2 (W2x);
// rows h2[p-2] -> z2 (W2h). A staged in 64KB LDS chunks (async-split);
// W streamed as uniform 32B/row from L2 (resident: no L2 invalidation).
__global__ void __launch_bounds__(512)
lstm_fused(const float* __restrict__ xT,
           const float* __restrict__ Wp1, const float* __restrict__ Wp2,
           const float* __restrict__ b1, const float* __restrict__ b2,
           float* __restrict__ pair0, float* __restrict__ pair1,
           float* __restrict__ xg, unsigned* __restrict__ bar)
{
  __shared__ float As[2][16384];          // 2 x 64KB chunk buffers (128 rows x 512B)

  const int tid = threadIdx.x;
  const int lane = tid & 63;
  const int wv = __builtin_amdgcn_readfirstlane(tid >> 6);
  const int blk = blockIdx.x;
  const int mg = blk & 15, jg = blk >> 4;  // XCD(blk)=blk%8=mg%8
  const int mgoff = mg << 7;               // 128 seqs per m-group
  const int jp = (jg << 3) + wv;           // jcol pair id 0..127
  const int jc0 = jp << 1;
  unsigned* mybar = bar + (mg << 4);

  const float* wp1 = Wp1 + (size_t)jp * (272 * 8);
  const float* wp2 = Wp2 + (size_t)jp * (512 * 8);

  float4 bA1, bB1, bA2, bB2;
  #pragma unroll
  for (int g = 0; g < 4; ++g) {
    (&bA1.x)[g] = b1[(g << 8) + jc0];
    (&bB1.x)[g] = b1[(g << 8) + jc0 + 1];
    (&bA2.x)[g] = b2[(g << 8) + jc0];
    (&bB2.x)[g] = b2[(g << 8) + jc0 + 1];
  }

  float c1[2][2] = {{0,0},{0,0}}, c2[2][2] = {{0,0},{0,0}}, pool[2][2] = {{0,0},{0,0}};
  float* const pr[2] = { pair0, pair1 };
  float z1[2][2][4], z2[2][2][4];

  auto stageLoad = [&](const float* base, int per, float4* S) {
    #pragma unroll
    for (int i = 0; i < 8; ++i) if (i < per) {
      const int seg = wv * per + i;                 // 1KB segment = 2 rows
      const int r = (seg << 1) + (lane >> 5);
      S[i] = *(const float4*)(base + (size_t)r * 2048 + ((lane & 31) << 2));
    }
  };
  auto dsWrite = [&](float* buf, int per, const float4* S) {
    #pragma unroll
    for (int i = 0; i < 8; ++i) if (i < per)
      ((float4*)buf)[(wv * per + i) * 64 + lane] = S[i];   // contiguous b128: conflict-free
  };

  auto cons_x = [&](const float* buf, const float* w1) {   // 16 rows -> z1
    float2 Aq[4]; float4 Wa[4], Wb[4];
    #pragma unroll
    for (int i = 0; i < 4; ++i) {
      Aq[i] = ((const float2*)(buf + (i << 7)))[lane];
      Wa[i] = *(const float4*)(w1 + (i << 3));
      Wb[i] = *(const float4*)(w1 + (i << 3) + 4);
    }
    #pragma unroll
    for (int k = 0; k < 16; ++k) {
      float2 a = Aq[k & 3]; float4 wa = Wa[k & 3], wb = Wb[k & 3];
      FMA16Z(z1, a, wa, wb);
      int kn = k + 4; kn = kn > 15 ? 15 : kn;
      Aq[k & 3] = ((const float2*)(buf + (kn << 7)))[lane];
      Wa[k & 3] = *(const float4*)(w1 + (kn << 3));
      Wb[k & 3] = *(const float4*)(w1 + (kn << 3) + 4);
    }
  };
  auto cons_dual = [&](const float* buf, const float* w1, const float* w2) {  // 128 rows -> z1+z2
    float2 Aq[4]; float4 W1a[4], W1b[4], W2a[4], W2b[4];
    #pragma unroll
    for (int i = 0; i < 4; ++i) {
      Aq[i] = ((const float2*)(buf + (i << 7)))[lane];
      W1a[i] = *(const float4*)(w1 + (i << 3));
      W1b[i] = *(const float4*)(w1 + (i << 3) + 4);
      W2a[i] = *(const float4*)(w2 + (i << 3));
      W2b[i] = *(const float4*)(w2 + (i << 3) + 4);
    }
    #pragma unroll 4
    for (int k = 0; k < 128; ++k) {
      float2 a = Aq[k & 3];
      float4 wa = W1a[k & 3], wb = W1b[k & 3];
      float4 va = W2a[k & 3], vb = W2b[k & 3];
      FMA16Z(z1, a, wa, wb);
      FMA16Z(z2, a, va, vb);
      int kn = k + 4; kn = kn > 127 ? 127 : kn;
      Aq[k & 3] = ((const float2*)(buf + (kn << 7)))[lane];
      W1a[k & 3] = *(const float4*)(w1 + (kn << 3));
      W1b[k & 3] = *(const float4*)(w1 + (kn << 3) + 4);
      W2a[k & 3] = *(const float4*)(w2 + (kn << 3));
      W2b[k & 3] = *(const float4*)(w2 + (kn << 3) + 4);
    }
  };
  auto cons_z2 = [&](const float* buf, const float* w2) {  // 128 rows -> z2
    float2 Aq[4]; float4 Wa[4], Wb[4];
    #pragma unroll
    for (int i = 0; i < 4; ++i) {
      Aq[i] = ((const float2*)(buf + (i << 7)))[lane];
      Wa[i] = *(const float4*)(w2 + (i << 3));
      Wb[i] = *(const float4*)(w2 + (i << 3) + 4);
    }
    #pragma unroll 4
    for (int k = 0; k < 128; ++k) {
      float2 a = Aq[k & 3]; float4 wa = Wa[k & 3], wb = Wb[k & 3];
      FMA16Z(z2, a, wa, wb);
      int kn = k + 4; kn = kn > 127 ? 127 : kn;
      Aq[k & 3] = ((const float2*)(buf + (kn << 7)))[lane];
      Wa[k & 3] = *(const float4*)(w2 + (kn << 3));
      Wb[k & 3] = *(const float4*)(w2 + (kn << 3) + 4);
    }
  };

  for (int p = 0; p <= TSTEPS; ++p) {
    float* const pw = pr[p & 1];
    const float* const prd = pr[(p + 1) & 1];
    const bool doL1 = (p < TSTEPS);

    // chunk plan
    const float* csrc[5]; int cw1[5], cw2[5], cmode[5], cper[5]; int nc = 0;
    if (doL1) { csrc[nc] = xT + (size_t)(p << 4) * 2048 + mgoff;
                cw1[nc] = 0; cw2[nc] = 0; cmode[nc] = 0; cper[nc] = 1; ++nc; }
    if (p >= 1) {
      const int md = doL1 ? 1 : 2;
      csrc[nc] = prd + mgoff;                        cw1[nc] = 16;  cw2[nc] = 0;   cmode[nc] = md; cper[nc] = 8; ++nc;
      csrc[nc] = prd + (size_t)128 * 2048 + mgoff;   cw1[nc] = 144; cw2[nc] = 128; cmode[nc] = md; cper[nc] = 8; ++nc;
    }
    if (p >= 2) {
      csrc[nc] = prd + (size_t)256 * 2048 + mgoff;   cw1[nc] = 0; cw2[nc] = 256; cmode[nc] = 2; cper[nc] = 8; ++nc;
      csrc[nc] = prd + (size_t)384 * 2048 + mgoff;   cw1[nc] = 0; cw2[nc] = 384; cmode[nc] = 2; cper[nc] = 8; ++nc;
    }

    if (doL1) {
      #pragma unroll
      for (int m = 0; m < 2; ++m) {
        z1[m][0][0] = bA1.x; z1[m][0][1] = bA1.y; z1[m][0][2] = bA1.z; z1[m][0][3] = bA1.w;
        z1[m][1][0] = bB1.x; z1[m][1][1] = bB1.y; z1[m][1][2] = bB1.z; z1[m][1][3] = bB1.w;
      }
    }
    if (p >= 1) {
      #pragma unroll
      for (int m = 0; m < 2; ++m) {
        z2[m][0][0] = bA2.x; z2[m][0][1] = bA2.y; z2[m][0][2] = bA2.z; z2[m][0][3] = bA2.w;
        z2[m][1][0] = bB2.x; z2[m][1][1] = bB2.y; z2[m][1][2] = bB2.z; z2[m][1][3] = bB2.w;
      }
    }

    // pipelined chunk loop (T14 split: load early, ds_write late)
    float4 S[8];
    stageLoad(csrc[0], cper[0], S);
    dsWrite(&As[0][0], cper[0], S);
    __syncthreads();
    int cur = 0;
    for (int c = 0; c < nc; ++c) {
      if (c + 1 < nc) stageLoad(csrc[c + 1], cper[c + 1], S);
      const float* buf = &As[cur][0];
      if (cmode[c] == 0)      cons_x(buf, wp1 + (cw1[c] << 3));
      else if (cmode[c] == 1) cons_dual(buf, wp1 + (cw1[c] << 3), wp2 + (cw2[c] << 3));
      else                    cons_z2(buf, wp2 + (cw2[c] << 3));
      if (c + 1 < nc) { dsWrite(&As[cur ^ 1][0], cper[c + 1], S); cur ^= 1; }
      __syncthreads();
    }

    // epilogues
    if (doL1) {
      float2 hv0, hv1;
      #pragma unroll
      for (int m = 0; m < 2; ++m) {
        #pragma unroll
        for (int j = 0; j < 2; ++j) {
          float iv = sigm(z1[m][j][0]), fv = sigm(z1[m][j][1]);
          float gv = tanhf(z1[m][j][2]), ov = sigm(z1[m][j][3]);
          c1[m][j] = fv * c1[m][j] + iv * gv;
          float h = ov * tanhf(c1[m][j]);
          if (j == 0) (&hv0.x)[m] = h; else (&hv1.x)[m] = h;
        }
      }
      ((float2*)(pw + (size_t)jc0 * 2048 + mgoff))[lane] = hv0;
      ((float2*)(pw + (size_t)(jc0 + 1) * 2048 + mgoff))[lane] = hv1;
    }
    if (p >= 1) {
      float2 hv0, hv1;
      #pragma unroll
      for (int m = 0; m < 2; ++m) {
        #pragma unroll
        for (int j = 0; j < 2; ++j) {
          float iv = sigm(z2[m][j][0]), fv = sigm(z2[m][j][1]);
          float gv = tanhf(z2[m][j][2]), ov = sigm(z2[m][j][3]);
          c2[m][j] = fv * c2[m][j] + iv * gv;
          float h = ov * tanhf(c2[m][j]);
          pool[m][j] += h;
          if (j == 0) (&hv0.x)[m] = h; else (&hv1.x)[m] = h;
        }
      }
      ((float2*)(pw + (size_t)(256 + jc0) * 2048 + mgoff))[lane] = hv0;
      ((float2*)(pw + (size_t)(257 + jc0) * 2048 + mgoff))[lane] = hv1;
    }

    if (p < TSTEPS) mg_barrier(mybar, (unsigned)(p + 1) * 16u);
  }

  #pragma unroll
  for (int m = 0; m < 2; ++m)
    #pragma unroll
    for (int j = 0; j < 2; ++j)
      xg[(size_t)(mgoff + (lane << 1) + m) * 256 + jc0 + j] = pool[m][j] * (1.0f / 50.0f);
}

// ---- GAT (verified R1-R4) ---------------------------------------------------
__global__ void __launch_bounds__(256)
gat_feat(const float* __restrict__ xin, const float* __restrict__ gW,
         const float* __restrict__ a_src, const float* __restrict__ a_dst,
         float* __restrict__ hfeat, float* __restrict__ es, float* __restrict__ ed)
{
  __shared__ float Xs[8][260];
  const int tid = threadIdx.x;
  const int r0 = blockIdx.x << 3;
  #pragma unroll
  for (int i = 0; i < 8; ++i) Xs[i][tid] = xin[((r0 + i) << 8) + tid];
  __syncthreads();
  float acc[8];
  #pragma unroll
  for (int i = 0; i < 8; ++i) acc[i] = 0.0f;
  for (int k = 0; k < 256; k += 4) {
    const float w0 = gW[(k + 0) * 256 + tid];
    const float w1 = gW[(k + 1) * 256 + tid];
    const float w2 = gW[(k + 2) * 256 + tid];
    const float w3 = gW[(k + 3) * 256 + tid];
    #pragma unroll
    for (int i = 0; i < 8; ++i)
      acc[i] += Xs[i][k] * w0 + Xs[i][k + 1] * w1 + Xs[i][k + 2] * w2 + Xs[i][k + 3] * w3;
  }
  const int h = tid >> 6;
  const int lane = tid & 63;
  const float asv = a_src[(h << 6) + lane];
  const float adv = a_dst[(h << 6) + lane];
  #pragma unroll
  for (int i = 0; i < 8; ++i) {
    hfeat[((r0 + i) << 8) + tid] = acc[i];
    float pse = acc[i] * asv;
    float pde = acc[i] * adv;
    #pragma unroll
    for (int off = 32; off > 0; off >>= 1) {
      pse += __shfl_down(pse, off);
      pde += __shfl_down(pde, off);
    }
    if (lane == 0) {
      es[((r0 + i) << 2) + h] = pse;
      ed[((r0 + i) << 2) + h] = pde;
    }
  }
}

__global__ void __launch_bounds__(256)
gat_out(const float* __restrict__ hfeat, const float* __restrict__ es, const float* __restrict__ ed,
        const float* __restrict__ gb, float* __restrict__ yout)
{
  __shared__ float exs[32][4];
  __shared__ float invden[4];
  const int tid = threadIdx.x;
  const int rbase = blockIdx.x << 5;
  if (tid < 128) {
    const int u = tid >> 2, h = tid & 3;
    float l = es[((rbase + u) << 2) + h] + ed[(rbase << 2) + h];
    exs[u][h] = (l < 0.0f) ? 0.2f * l : l;
  }
  __syncthreads();
  if (tid < 4) {
    const int h = tid;
    float m = -1e30f;
    for (int u = 0; u < 32; ++u) m = fmaxf(m, exs[u][h]);
    float s = 0.0f;
    for (int u = 0; u < 32; ++u) { float e = expf(exs[u][h] - m); exs[u][h] = e; s += e; }
    s += exs[0][h];                        // duplicate 0->0 edge
    invden[h] = 1.0f / (s + 1e-9f);
  }
  __syncthreads();
  const int h = tid >> 6;
  const float h0 = hfeat[(rbase << 8) + tid];
  float s = exs[0][h] * h0;
  for (int u = 0; u < 32; ++u)
    s += exs[u][h] * hfeat[((rbase + u) << 8) + tid];
  const float bias = gb[tid];
  const float inv1 = 1.0f / (1.0f + 1e-9f);
  yout[(rbase << 8) + tid] = gelu_t(s * invden[h] + bias);
  const float gv = gelu_t(h0 * inv1 + bias);
  for (int v = 1; v < 32; ++v)
    yout[((rbase + v) << 8) + tid] = gv;
}

// ---- launch -----------------------------------------------------------------
extern "C" void kernel_launch(void* const* d_in, const int* in_sizes, int n_in,
                              void* d_out, int out_size, void* d_ws, size_t ws_size,
                              hipStream_t stream) {
  (void)in_sizes; (void)n_in; (void)out_size; (void)ws_size;
  const float* states = (const float*)d_in[0];
  const float* Wx1 = (const float*)d_in[1];
  const float* Wh1 = (const float*)d_in[2];
  const float* b1  = (const float*)d_in[3];
  const float* Wx2 = (const float*)d_in[4];
  const float* Wh2 = (const float*)d_in[5];
  const float* b2  = (const float*)d_in[6];
  const float* gW1 = (const float*)d_in[7];
  const float* gas1 = (const float*)d_in[8];
  const float* gad1 = (const float*)d_in[9];
  const float* gb1 = (const float*)d_in[10];
  const float* gW2 = (const float*)d_in[11];
  const float* gas2 = (const float*)d_in[12];
  const float* gad2 = (const float*)d_in[13];
  const float* gb2 = (const float*)d_in[14];

  float* ws = (float*)d_ws;
  float* pair0 = ws;                       // 2*NB floats (h1|h2 plane)
  float* pair1 = ws + 2 * (size_t)NB;      // 2*NB floats
  float* xg    = ws + 4 * (size_t)NB;      // NB floats
  float* xT    = ws + 5 * (size_t)NB;      // 800*2048 floats
  float* Wp1   = xT + 800 * 2048;          // 128*272*8 = 278528
  float* Wp2   = Wp1 + 278528;             // 128*512*8 = 524288
  unsigned* bar = (unsigned*)(Wp2 + 524288);
  // GAT aliases (pair buffers dead after lstm)
  float* y1    = pair0;
  float* hfeat = pair0 + NB;
  float* es    = pair1;
  float* ed    = pair1 + 2048 * 4;
  float* dout  = (float*)d_out;

  pack_w<<<dim3(2048), dim3(256), 0, stream>>>(Wx1, Wh1, Wx2, Wh2, Wp1, Wp2, bar);
  transpose_x<<<dim3(32 * 13), dim3(256), 0, stream>>>(states, xT);

  void* args[] = { (void*)&xT, (void*)&Wp1, (void*)&Wp2, (void*)&b1, (void*)&b2,
                   (void*)&pair0, (void*)&pair1, (void*)&xg, (void*)&bar };
  hipError_t err = hipLaunchCooperativeKernel((void*)lstm_fused, dim3(256), dim3(512),
                                              args, 0, stream);
  (void)err;

  gat_feat<<<dim3(256), dim3(256), 0, stream>>>(xg, gW1, gas1, gad1, hfeat, es, ed);
  gat_out<<<dim3(64), dim3(256), 0, stream>>>(hfeat, es, ed, gb1, y1);
  gat_feat<<<dim3(256), dim3(256), 0, stream>>>(y1, gW2, gas2, gad2, hfeat, es, ed);
  gat_out<<<dim3(64), dim3(256), 0, stream>>>(hfeat, es, ed, gb2, dout);
}